// Round 1
// baseline (792.769 us; speedup 1.0000x reference)
//
#include <hip/hip_runtime.h>
#include <stdint.h>

typedef __bf16 bf16_t;
typedef __bf16 bf16x8 __attribute__((ext_vector_type(8)));
typedef __bf16 bf16x4 __attribute__((ext_vector_type(4)));
typedef float f32x4 __attribute__((ext_vector_type(4)));

// Async global->LDS, 16B per lane. LDS dest must be wave-uniform base + lane*16,
// which all call sites below satisfy (thread t writes LDS byte offset t*16 within
// a region, so wave w's lane 0 pointer is the wave-uniform base).
#define GLOAD16(gp, lp)                                                        \
    __builtin_amdgcn_global_load_lds(                                          \
        (const __attribute__((address_space(1))) void*)(gp),                   \
        (__attribute__((address_space(3))) void*)(lp), 16, 0, 0)

// ---------------------------------------------------------------------------
// fp32 -> bf16 convert with column-concat placement:
// dst[r*ldd + coff + c] = (bf16)src[r*cols + c], cols = 1<<cshift
// ---------------------------------------------------------------------------
__global__ __launch_bounds__(256) void cvt_kernel(const float* __restrict__ src,
                                                  bf16_t* __restrict__ dst,
                                                  int total4, int cshift,
                                                  int cmask, int ldd, int coff) {
    int i = blockIdx.x * 256 + threadIdx.x;
    if (i >= total4) return;
    int idx = i << 2;
    int r = idx >> cshift;
    int c = idx & cmask;
    float4 v = *(const float4*)(src + idx);
    bf16x4 o = {(bf16_t)v.x, (bf16_t)v.y, (bf16_t)v.z, (bf16_t)v.w};
    *(bf16x4*)(dst + (size_t)r * ldd + coff + c) = o;
}

// ---------------------------------------------------------------------------
// Small-N LoRA GEMM: t = 0.25 * (A[M x K] @ Bw[64 x K]^T), written as bf16 into
// dst columns [coff, coff+64). BM=64 per block, 4 waves each own 16 rows.
// ---------------------------------------------------------------------------
__global__ __launch_bounds__(256) void lora_kernel(const bf16_t* __restrict__ A,
                                                   int lda,
                                                   const bf16_t* __restrict__ Bw,
                                                   int K, bf16_t* __restrict__ dst,
                                                   int ldd, int coff) {
    __shared__ __align__(16) bf16_t As[64 * 32];
    __shared__ __align__(16) bf16_t Bs[64 * 32];
    const int t = threadIdx.x;
    const int m0 = blockIdx.x * 64;
    const int lane = t & 63, w = t >> 6;
    const int ln15 = lane & 15, q = lane >> 4;

    const bf16_t* ga = A + (size_t)(m0 + (t >> 2)) * lda + ((t & 3) << 3);
    const bf16_t* gb = Bw + (size_t)(t >> 2) * K + ((t & 3) << 3);
    bf16_t* lA = As + t * 8;
    bf16_t* lB = Bs + t * 8;

    const f32x4 z = {0.f, 0.f, 0.f, 0.f};
    f32x4 acc[4];
#pragma unroll
    for (int j = 0; j < 4; ++j) acc[j] = z;

    const int aoff = (w * 16 + ln15) * 32 + q * 8;

    for (int kt = 0; kt < K; kt += 32) {
        GLOAD16(ga, lA);
        GLOAD16(gb, lB);
        __syncthreads();
        bf16x8 av = *(const bf16x8*)(As + aoff);
#pragma unroll
        for (int j = 0; j < 4; ++j) {
            bf16x8 bv = *(const bf16x8*)(Bs + (j * 16 + ln15) * 32 + q * 8);
            acc[j] = __builtin_amdgcn_mfma_f32_16x16x32_bf16(av, bv, acc[j], 0, 0, 0);
        }
        __syncthreads();
        ga += 32;
        gb += 32;
    }

#pragma unroll
    for (int j = 0; j < 4; ++j)
#pragma unroll
        for (int rg = 0; rg < 4; ++rg) {
            int m = m0 + w * 16 + q * 4 + rg;
            int c = j * 16 + ln15;
            dst[(size_t)m * ldd + coff + c] = (bf16_t)(acc[j][rg] * 0.25f);
        }
}

// ---------------------------------------------------------------------------
// GEMM1 fused: gate_up = X1[8192 x 2112] @ Wc[8192 x 2112]^T with SwiGLU.
// Block computes 128 rows x (64 gate cols n0.. + 64 up cols 4096+n0..).
// Epilogue: h = up * silu(gate) -> bf16 into X2 columns [0,4096).
// ---------------------------------------------------------------------------
__global__ __launch_bounds__(256) void gemm1_kernel(const bf16_t* __restrict__ X,
                                                    const bf16_t* __restrict__ Wc,
                                                    bf16_t* __restrict__ X2) {
    constexpr int LDA = 2112, LDW = 2112, LDX2 = 4160, K = 2112;
    __shared__ __align__(16) bf16_t As[128 * 32];
    __shared__ __align__(16) bf16_t Bs[128 * 32];
    const int t = threadIdx.x;
    const int n0 = blockIdx.x * 64;   // h column block
    const int m0 = blockIdx.y * 128;  // token rows
    const int lane = t & 63, w = t >> 6, wr = w >> 1, wc = w & 1;
    const int ln15 = lane & 15, q = lane >> 4;

    const bf16_t* ga0 = X + (size_t)(m0 + (t >> 2)) * LDA + ((t & 3) << 3);
    const bf16_t* ga1 = ga0 + (size_t)64 * LDA;
    const bf16_t* gb0 = Wc + (size_t)(n0 + (t >> 2)) * LDW + ((t & 3) << 3);  // gate rows
    const bf16_t* gb1 = gb0 + (size_t)4096 * LDW;                             // up rows
    bf16_t* lA0 = As + t * 8;
    bf16_t* lA1 = As + 2048 + t * 8;
    bf16_t* lB0 = Bs + t * 8;
    bf16_t* lB1 = Bs + 2048 + t * 8;

    const f32x4 z = {0.f, 0.f, 0.f, 0.f};
    f32x4 accg[4][2], accu[4][2];
#pragma unroll
    for (int i = 0; i < 4; ++i)
#pragma unroll
        for (int j = 0; j < 2; ++j) {
            accg[i][j] = z;
            accu[i][j] = z;
        }

    int aoff[4], bgoff[2], buoff[2];
#pragma unroll
    for (int i = 0; i < 4; ++i) aoff[i] = (wr * 64 + i * 16 + ln15) * 32 + q * 8;
#pragma unroll
    for (int j = 0; j < 2; ++j) {
        bgoff[j] = (wc * 32 + j * 16 + ln15) * 32 + q * 8;
        buoff[j] = bgoff[j] + 64 * 32;
    }

    for (int kt = 0; kt < K; kt += 32) {
        GLOAD16(ga0, lA0);
        GLOAD16(ga1, lA1);
        GLOAD16(gb0, lB0);
        GLOAD16(gb1, lB1);
        __syncthreads();
        bf16x8 av[4], bg[2], bu[2];
#pragma unroll
        for (int i = 0; i < 4; ++i) av[i] = *(const bf16x8*)(As + aoff[i]);
#pragma unroll
        for (int j = 0; j < 2; ++j) {
            bg[j] = *(const bf16x8*)(Bs + bgoff[j]);
            bu[j] = *(const bf16x8*)(Bs + buoff[j]);
        }
#pragma unroll
        for (int i = 0; i < 4; ++i)
#pragma unroll
            for (int j = 0; j < 2; ++j) {
                accg[i][j] = __builtin_amdgcn_mfma_f32_16x16x32_bf16(av[i], bg[j], accg[i][j], 0, 0, 0);
                accu[i][j] = __builtin_amdgcn_mfma_f32_16x16x32_bf16(av[i], bu[j], accu[i][j], 0, 0, 0);
            }
        __syncthreads();
        ga0 += 32;
        ga1 += 32;
        gb0 += 32;
        gb1 += 32;
    }

#pragma unroll
    for (int i = 0; i < 4; ++i)
#pragma unroll
        for (int j = 0; j < 2; ++j)
#pragma unroll
            for (int rg = 0; rg < 4; ++rg) {
                int m = m0 + wr * 64 + i * 16 + q * 4 + rg;
                int d = n0 + wc * 32 + j * 16 + ln15;
                float g = accg[i][j][rg];
                float u = accu[i][j][rg];
                float h = u * g / (1.f + __expf(-g));  // up * silu(gate)
                X2[(size_t)m * LDX2 + d] = (bf16_t)h;
            }
}

// ---------------------------------------------------------------------------
// GEMM2: out = X2[8192 x 4160] @ Wdc[2048 x 4160]^T, fp32 out (8192 x 2048).
// Standard 128x128 tile, 4 waves 2x2, 4x4 mfma tiles per wave.
// ---------------------------------------------------------------------------
__global__ __launch_bounds__(256) void gemm2_kernel(const bf16_t* __restrict__ X2,
                                                    const bf16_t* __restrict__ Wdc,
                                                    float* __restrict__ out) {
    constexpr int LDA = 4160, LDB = 4160, K = 4160, LDO = 2048;
    __shared__ __align__(16) bf16_t As[128 * 32];
    __shared__ __align__(16) bf16_t Bs[128 * 32];
    const int t = threadIdx.x;
    const int n0 = blockIdx.x * 128;
    const int m0 = blockIdx.y * 128;
    const int lane = t & 63, w = t >> 6, wr = w >> 1, wc = w & 1;
    const int ln15 = lane & 15, q = lane >> 4;

    const bf16_t* ga0 = X2 + (size_t)(m0 + (t >> 2)) * LDA + ((t & 3) << 3);
    const bf16_t* ga1 = ga0 + (size_t)64 * LDA;
    const bf16_t* gb0 = Wdc + (size_t)(n0 + (t >> 2)) * LDB + ((t & 3) << 3);
    const bf16_t* gb1 = gb0 + (size_t)64 * LDB;
    bf16_t* lA0 = As + t * 8;
    bf16_t* lA1 = As + 2048 + t * 8;
    bf16_t* lB0 = Bs + t * 8;
    bf16_t* lB1 = Bs + 2048 + t * 8;

    const f32x4 z = {0.f, 0.f, 0.f, 0.f};
    f32x4 acc[4][4];
#pragma unroll
    for (int i = 0; i < 4; ++i)
#pragma unroll
        for (int j = 0; j < 4; ++j) acc[i][j] = z;

    int aoff[4], boff[4];
#pragma unroll
    for (int i = 0; i < 4; ++i) {
        aoff[i] = (wr * 64 + i * 16 + ln15) * 32 + q * 8;
        boff[i] = (wc * 64 + i * 16 + ln15) * 32 + q * 8;
    }

    for (int kt = 0; kt < K; kt += 32) {
        GLOAD16(ga0, lA0);
        GLOAD16(ga1, lA1);
        GLOAD16(gb0, lB0);
        GLOAD16(gb1, lB1);
        __syncthreads();
        bf16x8 av[4], bv[4];
#pragma unroll
        for (int i = 0; i < 4; ++i) {
            av[i] = *(const bf16x8*)(As + aoff[i]);
            bv[i] = *(const bf16x8*)(Bs + boff[i]);
        }
#pragma unroll
        for (int i = 0; i < 4; ++i)
#pragma unroll
            for (int j = 0; j < 4; ++j)
                acc[i][j] = __builtin_amdgcn_mfma_f32_16x16x32_bf16(av[i], bv[j], acc[i][j], 0, 0, 0);
        __syncthreads();
        ga0 += 32;
        ga1 += 32;
        gb0 += 32;
        gb1 += 32;
    }

#pragma unroll
    for (int i = 0; i < 4; ++i)
#pragma unroll
        for (int j = 0; j < 4; ++j)
#pragma unroll
            for (int rg = 0; rg < 4; ++rg) {
                int m = m0 + wr * 64 + i * 16 + q * 4 + rg;
                int n = n0 + wc * 64 + j * 16 + ln15;
                out[(size_t)m * LDO + n] = acc[i][j][rg];
            }
}

// ---------------------------------------------------------------------------
// Workspace layout (bytes):
//   X1  @ 0         : 8192 x 2112 bf16 = 34,603,008   [x | 0.25*x@A_gu^T]
//   W1  @ 34603008  : 8192 x 2112 bf16 = 34,603,008   [W_gu | B_gu]
//   X2  @ 69206016  : 8192 x 4160 bf16 = 68,157,440   [h | 0.25*h@A_d^T]
//   W2  @ 137363456 : 2048 x 4160 bf16 = 17,039,360   [W_d | B_d]
//   Ag  @ 154402816 : 64 x 2048 bf16   = 262,144
//   Adb @ 154664960 : 64 x 4096 bf16   = 524,288
// total ~155.2 MB
// ---------------------------------------------------------------------------
extern "C" void kernel_launch(void* const* d_in, const int* in_sizes, int n_in,
                              void* d_out, int out_size, void* d_ws, size_t ws_size,
                              hipStream_t stream) {
    const float* x = (const float*)d_in[0];
    const float* Wgu = (const float*)d_in[1];
    const float* Agu = (const float*)d_in[2];
    const float* Bgu = (const float*)d_in[3];
    const float* Wd = (const float*)d_in[4];
    const float* Ad = (const float*)d_in[5];
    const float* Bd = (const float*)d_in[6];
    float* out = (float*)d_out;

    char* ws = (char*)d_ws;
    bf16_t* X1 = (bf16_t*)(ws);
    bf16_t* W1 = (bf16_t*)(ws + 34603008);
    bf16_t* X2 = (bf16_t*)(ws + 69206016);
    bf16_t* W2 = (bf16_t*)(ws + 137363456);
    bf16_t* Ag = (bf16_t*)(ws + 154402816);
    bf16_t* Adb = (bf16_t*)(ws + 154664960);

    // fp32 -> bf16 conversions with K-concat placement
    cvt_kernel<<<16384, 256, 0, stream>>>(x, X1, 4194304, 11, 2047, 2112, 0);
    cvt_kernel<<<16384, 256, 0, stream>>>(Wgu, W1, 4194304, 11, 2047, 2112, 0);
    cvt_kernel<<<512, 256, 0, stream>>>(Bgu, W1, 131072, 6, 63, 2112, 2048);
    cvt_kernel<<<128, 256, 0, stream>>>(Agu, Ag, 32768, 11, 2047, 2048, 0);
    cvt_kernel<<<8192, 256, 0, stream>>>(Wd, W2, 2097152, 12, 4095, 4160, 0);
    cvt_kernel<<<128, 256, 0, stream>>>(Bd, W2, 32768, 6, 63, 4160, 4096);
    cvt_kernel<<<256, 256, 0, stream>>>(Ad, Adb, 65536, 12, 4095, 4096, 0);

    // t1 = 0.25 * x @ A_gu^T  -> X1 cols [2048,2112)
    lora_kernel<<<128, 256, 0, stream>>>(X1, 2112, Ag, 2048, X1, 2112, 2048);
    // fused gate_up GEMM + SwiGLU -> X2 cols [0,4096)
    gemm1_kernel<<<dim3(64, 64), 256, 0, stream>>>(X1, W1, X2);
    // t2 = 0.25 * h @ A_d^T -> X2 cols [4096,4160)
    lora_kernel<<<128, 256, 0, stream>>>(X2, 4160, Adb, 4096, X2, 4160, 4096);
    // out = X2 @ [W_d|B_d]^T
    gemm2_kernel<<<dim3(16, 64), 256, 0, stream>>>(X2, W2, out);
}